// Round 1
// baseline (522.822 us; speedup 1.0000x reference)
//
#include <hip/hip_runtime.h>
#include <math.h>

#define BTOT   65536   // total rows (16*4096)
#define DDIM   256
#define KC     1024
#define RROWS  64      // rows per block
#define DB     16      // d-chunk
#define NTHR   512

// ws layout (floats):
// [0,1024)    psum  (sum over rows of softmax probs, per code)
// [1024,2048) counts (hard usage, as float)
// [2048,3072) e2    (||e_k||^2)
// [3072]      sum of min-distances
// total 12,320 bytes zero-initialized

// ---------------- ||e_k||^2 ----------------
__global__ void vq_e2(const float* __restrict__ embed, float* __restrict__ e2g) {
    int gt = blockIdx.x * blockDim.x + threadIdx.x;
    int k = gt >> 6;
    int lane = gt & 63;
    float4 v = *(const float4*)(embed + (size_t)k * DDIM + lane * 4);
    float s = v.x * v.x + v.y * v.y + v.z * v.z + v.w * v.w;
    #pragma unroll
    for (int off = 1; off < 64; off <<= 1) s += __shfl_xor(s, off);
    if (lane == 0) e2g[k] = s;
}

// ---------------- main fused GEMM + softmax/argmax ----------------
__global__ __launch_bounds__(NTHR, 2)
void vq_main(const float* __restrict__ z, const float* __restrict__ embed,
             const float* __restrict__ e2g,
             float* __restrict__ psum_g, float* __restrict__ counts_g,
             float* __restrict__ distsum_g, float* __restrict__ codes_f_out)
{
    __shared__ float eT[DB][KC];       // 64 KB, transposed embed chunk
    __shared__ float zT[DB][RROWS];    // 4 KB, transposed z chunk
    __shared__ float z2row[RROWS];
    __shared__ float psum_lds[KC];     // 4 KB
    __shared__ float wave_dist[8];

    const int tid  = threadIdx.x;
    const int w    = tid >> 6;
    const int lane = tid & 63;
    const int w8    = w << 3;
    const int lane4 = lane << 2;
    const int row0 = blockIdx.x * RROWS;

    float acc[8][16];
    #pragma unroll
    for (int r = 0; r < 8; ++r)
        #pragma unroll
        for (int c = 0; c < 16; ++c) acc[r][c] = 0.0f;

    float zsq = 0.0f;

    for (int cb = 0; cb < DDIM / DB; ++cb) {
        // stage embed chunk (transposed): 16*1024 floats
        #pragma unroll
        for (int it = 0; it < 8; ++it) {
            int idx = it * NTHR + tid;
            int k = idx >> 2;
            int dg = (idx & 3) << 2;
            float4 v = *(const float4*)(embed + (size_t)k * DDIM + cb * DB + dg);
            eT[dg + 0][k] = v.x;
            eT[dg + 1][k] = v.y;
            eT[dg + 2][k] = v.z;
            eT[dg + 3][k] = v.w;
        }
        // stage z chunk (transposed): 16*64 floats
        if (tid < 256) {
            int rr = tid >> 2;
            int dg = (tid & 3) << 2;
            float4 v = *(const float4*)(z + (size_t)(row0 + rr) * DDIM + cb * DB + dg);
            zT[dg + 0][rr] = v.x;
            zT[dg + 1][rr] = v.y;
            zT[dg + 2][rr] = v.z;
            zT[dg + 3][rr] = v.w;
            zsq += v.x * v.x + v.y * v.y + v.z * v.z + v.w * v.w;
        }
        __syncthreads();
        #pragma unroll
        for (int dd = 0; dd < DB; ++dd) {
            float4 za = *(const float4*)&zT[dd][w8];
            float4 zb = *(const float4*)&zT[dd][w8 + 4];
            float4 ea = *(const float4*)&eT[dd][lane4];
            float4 eb = *(const float4*)&eT[dd][lane4 + 256];
            float4 ec = *(const float4*)&eT[dd][lane4 + 512];
            float4 ed = *(const float4*)&eT[dd][lane4 + 768];
            float zv[8]  = {za.x, za.y, za.z, za.w, zb.x, zb.y, zb.z, zb.w};
            float ev[16] = {ea.x, ea.y, ea.z, ea.w, eb.x, eb.y, eb.z, eb.w,
                            ec.x, ec.y, ec.z, ec.w, ed.x, ed.y, ed.z, ed.w};
            #pragma unroll
            for (int r = 0; r < 8; ++r)
                #pragma unroll
                for (int c = 0; c < 16; ++c)
                    acc[r][c] = fmaf(zv[r], ev[c], acc[r][c]);
        }
        __syncthreads();
    }

    // ||z||^2 per row: 4 staging threads per row hold partials
    if (tid < 256) {
        zsq += __shfl_xor(zsq, 1);
        zsq += __shfl_xor(zsq, 2);
        if ((tid & 3) == 0) z2row[tid >> 2] = zsq;
    }
    __syncthreads();

    // e2 for this lane's 16 columns (k = (c>>2)*256 + lane*4 + (c&3))
    float e2v[16];
    {
        float4 a = *(const float4*)(e2g + lane4);
        float4 b = *(const float4*)(e2g + lane4 + 256);
        float4 c4 = *(const float4*)(e2g + lane4 + 512);
        float4 d4 = *(const float4*)(e2g + lane4 + 768);
        e2v[0] = a.x;  e2v[1] = a.y;  e2v[2] = a.z;  e2v[3] = a.w;
        e2v[4] = b.x;  e2v[5] = b.y;  e2v[6] = b.z;  e2v[7] = b.w;
        e2v[8] = c4.x; e2v[9] = c4.y; e2v[10] = c4.z; e2v[11] = c4.w;
        e2v[12] = d4.x; e2v[13] = d4.y; e2v[14] = d4.z; e2v[15] = d4.w;
    }

    float psum[16];
    #pragma unroll
    for (int c = 0; c < 16; ++c) psum[c] = 0.0f;
    float dist_local = 0.0f;

    #pragma unroll
    for (int r = 0; r < 8; ++r) {
        // logits in place; local max + argmax (k ascending in c => first-tie kept)
        float m = -INFINITY; int am = 0;
        #pragma unroll
        for (int c = 0; c < 16; ++c) {
            float l = fmaf(2.0f, acc[r][c], -e2v[c]);
            acc[r][c] = l;
            int kidx = ((c >> 2) << 8) + lane4 + (c & 3);
            if (l > m) { m = l; am = kidx; }
        }
        // wave argmax reduce, ties -> lower index (matches jnp.argmin first-index)
        #pragma unroll
        for (int off = 1; off < 64; off <<= 1) {
            float om = __shfl_xor(m, off);
            int   oa = __shfl_xor(am, off);
            if (om > m || (om == m && oa < am)) { m = om; am = oa; }
        }
        // softmax sum (logits <= m, no overflow)
        float s = 0.0f;
        #pragma unroll
        for (int c = 0; c < 16; ++c) {
            float e = __expf(acc[r][c] - m);
            acc[r][c] = e;
            s += e;
        }
        #pragma unroll
        for (int off = 1; off < 64; off <<= 1) s += __shfl_xor(s, off);
        float inv = 1.0f / s;
        #pragma unroll
        for (int c = 0; c < 16; ++c) psum[c] = fmaf(acc[r][c], inv, psum[c]);

        if (lane == 0) {
            int b = row0 + w8 + r;
            codes_f_out[b] = (float)am;
            atomicAdd(&counts_g[am], 1.0f);
            dist_local += z2row[w8 + r] - m;   // ||z||^2 - max logit = min dist
        }
    }
    if (lane == 0) wave_dist[w] = dist_local;

    // block-level softmax-prob accumulation, then one global atomic per code
    for (int t = tid; t < KC; t += NTHR) psum_lds[t] = 0.0f;
    __syncthreads();
    #pragma unroll
    for (int c = 0; c < 16; ++c) {
        int kidx = ((c >> 2) << 8) + lane4 + (c & 3);
        atomicAdd(&psum_lds[kidx], psum[c]);
    }
    __syncthreads();
    for (int t = tid; t < KC; t += NTHR) atomicAdd(&psum_g[t], psum_lds[t]);
    if (tid == 0) {
        float ds = 0.0f;
        #pragma unroll
        for (int i = 0; i < 8; ++i) ds += wave_dist[i];
        atomicAdd(distsum_g, ds);
    }
}

// ---------------- gather z_q = embed[codes] ----------------
__global__ void vq_gather(const float* __restrict__ embed,
                          const float* __restrict__ codes_f,
                          float* __restrict__ outq)
{
    int idx = blockIdx.x * 256 + threadIdx.x;   // [0, 4194304)
    int b = idx >> 6;
    int c = (int)codes_f[b];
    ((float4*)outq)[idx] = ((const float4*)embed)[(c << 6) + (idx & 63)];
}

// ---------------- finalize scalars ----------------
__global__ void vq_finalize(const float* __restrict__ psum_g,
                            const float* __restrict__ counts_g,
                            const float* __restrict__ distsum_g,
                            float* __restrict__ out_s)
{
    __shared__ float s1[16], s2[16];
    int tid = threadIdx.x;           // 1024 threads
    float a = psum_g[tid] * (1.0f / 65536.0f);
    float e1 = -a * logf(a + 1e-10f);
    float h = counts_g[tid] * (1.0f / 65536.0f);
    float e2 = -h * logf(h + 1e-10f);
    #pragma unroll
    for (int off = 1; off < 64; off <<= 1) {
        e1 += __shfl_xor(e1, off);
        e2 += __shfl_xor(e2, off);
    }
    int w = tid >> 6, lane = tid & 63;
    if (lane == 0) { s1[w] = e1; s2[w] = e2; }
    __syncthreads();
    if (tid == 0) {
        float E1 = 0.0f, E2 = 0.0f;
        #pragma unroll
        for (int i = 0; i < 16; ++i) { E1 += s1[i]; E2 += s2[i]; }
        float commit = distsum_g[0] * (1.0f / 16777216.0f);
        out_s[0] = commit;                       // commitment_loss
        out_s[1] = commit;                       // codebook_loss (identical value)
        out_s[2] = -E1 / 6.9314718055994531f;    // diversity_loss
        out_s[3] = E1;                           // usage_entropy
        out_s[4] = __expf(E2);                   // perplexity
    }
}

extern "C" void kernel_launch(void* const* d_in, const int* in_sizes, int n_in,
                              void* d_out, int out_size, void* d_ws, size_t ws_size,
                              hipStream_t stream) {
    const float* z     = (const float*)d_in[0];
    const float* embed = (const float*)d_in[1];

    float* out      = (float*)d_out;
    float* zq_out   = out;                  // 16777216
    float* codes_f  = out + 16777216;       // 65536
    float* scalars  = out + 16842752;       // 5

    float* ws        = (float*)d_ws;
    float* psum_g    = ws;
    float* counts_g  = ws + 1024;
    float* e2g       = ws + 2048;
    float* distsum_g = ws + 3072;

    hipMemsetAsync(d_ws, 0, 3080 * sizeof(float), stream);
    vq_e2<<<256, 256, 0, stream>>>(embed, e2g);
    vq_main<<<BTOT / RROWS, NTHR, 0, stream>>>(z, embed, e2g, psum_g, counts_g,
                                               distsum_g, codes_f);
    vq_gather<<<4194304 / 256, 256, 0, stream>>>(embed, codes_f, zq_out);
    vq_finalize<<<1, 1024, 0, stream>>>(psum_g, counts_g, distsum_g, scalars);
}

// Round 2
// 202.126 us; speedup vs baseline: 2.5866x; 2.5866x over previous
//
#include <hip/hip_runtime.h>
#include <math.h>

typedef _Float16 half8 __attribute__((ext_vector_type(8)));
typedef float f32x4 __attribute__((ext_vector_type(4)));

#define AS1 __attribute__((address_space(1)))
#define AS3 __attribute__((address_space(3)))

#define BTOT   65536
#define DDIM   256
#define KC     1024

// ---------------- ||e_k||^2 ----------------
__global__ void vq_e2(const float* __restrict__ embed, float* __restrict__ e2g) {
    int gt = blockIdx.x * blockDim.x + threadIdx.x;
    int k = gt >> 6;
    int lane = gt & 63;
    float4 v = *(const float4*)(embed + (size_t)k * DDIM + lane * 4);
    float s = v.x * v.x + v.y * v.y + v.z * v.z + v.w * v.w;
    #pragma unroll
    for (int off = 1; off < 64; off <<= 1) s += __shfl_xor(s, off);
    if (lane == 0) e2g[k] = s;
}

// ---------------- prep: embed -> fp16 hi/lo pre-swizzled LDS image in ws ----
// 32 chunks of 32768B. chunk id = kc*4 + p*2 + h  (p: 0=hi 1=lo, h: col-half)
// within chunk: local col cl (512) * 64B; 16B slot s stored at (s ^ (c&3))*16,
// content = fp16(embed[c][kc*32 + s*8 .. +8])
__global__ void vq_prep(const float* __restrict__ embed, char* __restrict__ wsB) {
    int id = blockIdx.x * 256 + threadIdx.x;   // 32768 total
    int c  = id >> 5;
    int kc = (id >> 2) & 7;
    int s  = id & 3;
    const float* src = embed + (size_t)c * DDIM + kc * 32 + s * 8;
    half8 hi, lo;
    #pragma unroll
    for (int j = 0; j < 8; ++j) {
        float xv = src[j];
        _Float16 hh = (_Float16)xv;
        hi[j] = hh;
        lo[j] = (_Float16)(xv - (float)hh);
    }
    int h = c >> 9, cl = c & 511;
    int inner = cl * 64 + ((s ^ (c & 3)) << 4);
    *(half8*)(wsB + (size_t)(kc * 4 + h) * 32768 + inner) = hi;
    *(half8*)(wsB + (size_t)(kc * 4 + 2 + h) * 32768 + inner) = lo;
}

// ---------------- main fused MFMA GEMM + softmax/argmax ----------------
__global__ __launch_bounds__(512, 2)
void vq_main(const float* __restrict__ z, const char* __restrict__ wsB,
             const float* __restrict__ e2g, float* __restrict__ psum_g,
             float* __restrict__ counts_g, float* __restrict__ distsum_g,
             float* __restrict__ codes_f_out)
{
    __shared__ __align__(16) char ldsA[65536];      // A hi at 0, lo at 32768
    __shared__ __align__(16) char ldsB[2][32768];   // double-buffered B stage
    __shared__ float psum_lds[KC];
    __shared__ float lmax[64][8];
    __shared__ int   larg[64][8];
    __shared__ float lsum[64][8];
    __shared__ float rowM[64];
    __shared__ float rowInv[64];
    __shared__ float z2row[64];

    const int tid  = threadIdx.x;
    const int w    = tid >> 6;
    const int lane = tid & 63;
    const int row0 = blockIdx.x * 64;
    // per-lane swizzled fragment base: (lane&15)*64 + ((lane>>4)^(lane&3))*16
    const int bA = (lane & 15) * 64 + (((lane >> 4) ^ (lane & 3)) << 4);

    psum_lds[tid] = 0.f;
    psum_lds[tid + 512] = 0.f;

    // ---- A staging: 64 rows of z -> fp16 hi/lo swizzled in LDS ----
    {
        const int ar = tid >> 3;     // row 0..63
        const int kc = tid & 7;      // k-chunk 0..7 (32 d each)
        const float* src = z + (size_t)(row0 + ar) * DDIM + kc * 32;
        float x[32];
        #pragma unroll
        for (int j = 0; j < 8; ++j) {
            float4 v = ((const float4*)src)[j];
            x[4*j] = v.x; x[4*j+1] = v.y; x[4*j+2] = v.z; x[4*j+3] = v.w;
        }
        float zsq = 0.f;
        #pragma unroll
        for (int j = 0; j < 32; ++j) zsq = fmaf(x[j], x[j], zsq);
        zsq += __shfl_xor(zsq, 1);
        zsq += __shfl_xor(zsq, 2);
        zsq += __shfl_xor(zsq, 4);
        if ((tid & 7) == 0) z2row[ar] = zsq;
        #pragma unroll
        for (int s = 0; s < 4; ++s) {
            half8 hi, lo;
            #pragma unroll
            for (int j = 0; j < 8; ++j) {
                float xv = x[8*s + j];
                _Float16 hh = (_Float16)xv;
                hi[j] = hh;
                lo[j] = (_Float16)(xv - (float)hh);
            }
            int off = kc * 4096 + ar * 64 + ((s ^ (ar & 3)) << 4);
            *(half8*)(ldsA + off) = hi;
            *(half8*)(ldsA + 32768 + off) = lo;
        }
    }
    // issue stage-0 B loads
    {
        const char* gs = wsB + tid * 16;
        char* ld = &ldsB[0][tid * 16];
        #pragma unroll
        for (int r = 0; r < 4; ++r)
            __builtin_amdgcn_global_load_lds((AS1 const void*)(gs + r * 8192),
                                             (AS3 void*)(ld + r * 8192), 16, 0, 0);
    }
    __syncthreads();   // A visible to all; stage-0 loads drained

    f32x4 acc[4][8];
    #pragma unroll
    for (int rt = 0; rt < 4; ++rt)
        #pragma unroll
        for (int cg = 0; cg < 8; ++cg)
            acc[rt][cg] = (f32x4){0.f, 0.f, 0.f, 0.f};

    half8 aHi[4], aLo[4];

    // 32 stages: kc(8) x p(hi,lo) x h(col-half)
    #pragma unroll
    for (int kc = 0; kc < 8; ++kc) {
        #pragma unroll
        for (int p = 0; p < 2; ++p) {
            #pragma unroll
            for (int h = 0; h < 2; ++h) {
                const int s = kc * 4 + p * 2 + h;
                // own prev-issued loads for buf[s&1] complete, then barrier
                asm volatile("s_waitcnt vmcnt(0)\n\ts_barrier" ::: "memory");
                if (s + 1 < 32) {   // prefetch next stage (overlaps compute)
                    const char* gs = wsB + (size_t)(s + 1) * 32768 + tid * 16;
                    char* ld = &ldsB[(s + 1) & 1][tid * 16];
                    #pragma unroll
                    for (int r = 0; r < 4; ++r)
                        __builtin_amdgcn_global_load_lds((AS1 const void*)(gs + r * 8192),
                                                         (AS3 void*)(ld + r * 8192), 16, 0, 0);
                }
                if (p == 0 && h == 0) {
                    #pragma unroll
                    for (int rt = 0; rt < 4; ++rt) {
                        aHi[rt] = *(const half8*)(ldsA + kc * 4096 + rt * 1024 + bA);
                        aLo[rt] = *(const half8*)(ldsA + 32768 + kc * 4096 + rt * 1024 + bA);
                    }
                }
                const char* bb = &ldsB[s & 1][w * 4096 + bA];
                #pragma unroll
                for (int ct = 0; ct < 4; ++ct) {
                    half8 bf = *(const half8*)(bb + ct * 1024);
                    const int cg = h * 4 + ct;
                    #pragma unroll
                    for (int rt = 0; rt < 4; ++rt) {
                        acc[rt][cg] = __builtin_amdgcn_mfma_f32_16x16x32_f16(
                            aHi[rt], bf, acc[rt][cg], 0, 0, 0);
                        if (p == 0)
                            acc[rt][cg] = __builtin_amdgcn_mfma_f32_16x16x32_f16(
                                aLo[rt], bf, acc[rt][cg], 0, 0, 0);
                    }
                }
            }
        }
    }

    // ---- epilogue ----
    // wave w owns cols {64w..64w+63} U {512+64w..512+64w+63}
    // C/D layout: col = lane&15, row = (lane>>4)*4 + i
    int colv[8];
    float e2v[8];
    #pragma unroll
    for (int cg = 0; cg < 8; ++cg) {
        int colbase = (cg < 4) ? (w * 64 + cg * 16) : (512 + w * 64 + (cg - 4) * 16);
        colv[cg] = colbase + (lane & 15);
        e2v[cg] = e2g[colv[cg]];
    }
    // pass 1: per-wave local max/argmax per row
    #pragma unroll
    for (int rt = 0; rt < 4; ++rt) {
        #pragma unroll
        for (int i = 0; i < 4; ++i) {
            float m = -INFINITY; int am = 0x7fffffff;
            #pragma unroll
            for (int cg = 0; cg < 8; ++cg) {
                float l = fmaf(2.f, acc[rt][cg][i], -e2v[cg]);
                if (l > m) { m = l; am = colv[cg]; }
            }
            #pragma unroll
            for (int off = 1; off < 16; off <<= 1) {
                float om = __shfl_xor(m, off);
                int   oa = __shfl_xor(am, off);
                if (om > m || (om == m && oa < am)) { m = om; am = oa; }
            }
            if ((lane & 15) == 0) {
                int r = rt * 16 + ((lane >> 4) << 2) + i;
                lmax[r][w] = m; larg[r][w] = am;
            }
        }
    }
    __syncthreads();
    // pass 2: cross-wave reduce; codes, counts, min-dist
    if (tid < 64) {
        float M = -INFINITY; int A = 0x7fffffff;
        #pragma unroll
        for (int ww = 0; ww < 8; ++ww) {
            float mm = lmax[tid][ww]; int aa = larg[tid][ww];
            if (mm > M || (mm == M && aa < A)) { M = mm; A = aa; }
        }
        rowM[tid] = M;
        codes_f_out[row0 + tid] = (float)A;
        atomicAdd(&counts_g[A], 1.0f);
        float d = z2row[tid] - M;    // min dist = ||z||^2 - max logit
        #pragma unroll
        for (int off = 1; off < 64; off <<= 1) d += __shfl_xor(d, off);
        if (tid == 0) atomicAdd(distsum_g, d);
    }
    __syncthreads();
    // pass 3: exp and local sums
    #pragma unroll
    for (int rt = 0; rt < 4; ++rt) {
        #pragma unroll
        for (int i = 0; i < 4; ++i) {
            const int r = rt * 16 + ((lane >> 4) << 2) + i;
            float M = rowM[r];
            float ss = 0.f;
            #pragma unroll
            for (int cg = 0; cg < 8; ++cg) {
                float e = __expf(fmaf(2.f, acc[rt][cg][i], -e2v[cg]) - M);
                acc[rt][cg][i] = e;
                ss += e;
            }
            #pragma unroll
            for (int off = 1; off < 16; off <<= 1) ss += __shfl_xor(ss, off);
            if ((lane & 15) == 0) lsum[r][w] = ss;
        }
    }
    __syncthreads();
    // pass 4: row denominators
    if (tid < 64) {
        float S = 0.f;
        #pragma unroll
        for (int ww = 0; ww < 8; ++ww) S += lsum[tid][ww];
        rowInv[tid] = 1.0f / S;
    }
    __syncthreads();
    // pass 5: per-code prob sums
    #pragma unroll
    for (int cg = 0; cg < 8; ++cg) {
        float cp = 0.f;
        #pragma unroll
        for (int rt = 0; rt < 4; ++rt)
            #pragma unroll
            for (int i = 0; i < 4; ++i)
                cp = fmaf(acc[rt][cg][i], rowInv[rt * 16 + ((lane >> 4) << 2) + i], cp);
        atomicAdd(&psum_lds[colv[cg]], cp);
    }
    __syncthreads();
    atomicAdd(&psum_g[tid], psum_lds[tid]);
    atomicAdd(&psum_g[tid + 512], psum_lds[tid + 512]);
}

// ---------------- gather z_q = embed[codes] ----------------
__global__ void vq_gather(const float* __restrict__ embed,
                          const float* __restrict__ codes_f,
                          float* __restrict__ outq)
{
    int idx = blockIdx.x * 256 + threadIdx.x;   // [0, 4194304)
    int b = idx >> 6;
    int c = (int)codes_f[b];
    ((float4*)outq)[idx] = ((const float4*)embed)[(c << 6) + (idx & 63)];
}

// ---------------- finalize scalars ----------------
__global__ void vq_finalize(const float* __restrict__ psum_g,
                            const float* __restrict__ counts_g,
                            const float* __restrict__ distsum_g,
                            float* __restrict__ out_s)
{
    __shared__ float s1[16], s2[16];
    int tid = threadIdx.x;           // 1024 threads
    float a = psum_g[tid] * (1.0f / 65536.0f);
    float e1 = -a * logf(a + 1e-10f);
    float h = counts_g[tid] * (1.0f / 65536.0f);
    float e2 = -h * logf(h + 1e-10f);
    #pragma unroll
    for (int off = 1; off < 64; off <<= 1) {
        e1 += __shfl_xor(e1, off);
        e2 += __shfl_xor(e2, off);
    }
    int w = tid >> 6, lane = tid & 63;
    if (lane == 0) { s1[w] = e1; s2[w] = e2; }
    __syncthreads();
    if (tid == 0) {
        float E1 = 0.0f, E2 = 0.0f;
        #pragma unroll
        for (int i = 0; i < 16; ++i) { E1 += s1[i]; E2 += s2[i]; }
        float commit = distsum_g[0] * (1.0f / 16777216.0f);
        out_s[0] = commit;
        out_s[1] = commit;
        out_s[2] = -E1 / 6.9314718055994531f;
        out_s[3] = E1;
        out_s[4] = __expf(E2);
    }
}

extern "C" void kernel_launch(void* const* d_in, const int* in_sizes, int n_in,
                              void* d_out, int out_size, void* d_ws, size_t ws_size,
                              hipStream_t stream) {
    const float* z     = (const float*)d_in[0];
    const float* embed = (const float*)d_in[1];

    float* out      = (float*)d_out;
    float* zq_out   = out;                  // 16777216
    float* codes_f  = out + 16777216;       // 65536
    float* scalars  = out + 16842752;       // 5

    float* ws        = (float*)d_ws;
    float* psum_g    = ws;                  // 1024
    float* counts_g  = ws + 1024;           // 1024
    float* e2g       = ws + 2048;           // 1024
    float* distsum_g = ws + 3072;           // 1
    char*  wsB       = (char*)d_ws + 16384; // 1 MB fp16 image

    hipMemsetAsync(d_ws, 0, 3080 * sizeof(float), stream);
    vq_prep<<<128, 256, 0, stream>>>(embed, wsB);
    vq_e2<<<256, 256, 0, stream>>>(embed, e2g);
    vq_main<<<BTOT / 64, 512, 0, stream>>>(z, wsB, e2g, psum_g, counts_g,
                                           distsum_g, codes_f);
    vq_gather<<<4194304 / 256, 256, 0, stream>>>(embed, codes_f, zq_out);
    vq_finalize<<<1, 1024, 0, stream>>>(psum_g, counts_g, distsum_g, scalars);
}